// Round 6
// baseline (389.245 us; speedup 1.0000x reference)
//
#include <hip/hip_runtime.h>
#include <stdint.h>

#define KNN 16
#define LROWS 8
#define KBQ 8     // queries per knn block
#define KCAP 128  // survivor cap per query (E[survivors]~17, rank-stat)

// ---------------------------------------------------------------------------
// prep: per-batch [start,end) in parallel (replaces per-block binary search)
// ---------------------------------------------------------------------------
__global__ void prep_bounds(const int* __restrict__ bidx, int N,
                            int* __restrict__ starts, int* __restrict__ ends) {
  int i = blockIdx.x * 256 + threadIdx.x;
  if (i >= N) return;
  int b = bidx[i];
  if (i == 0 || bidx[i - 1] != b) starts[b] = i;
  if (i == N - 1 || bidx[i + 1] != b) ends[b] = i + 1;
}

// ---------------------------------------------------------------------------
// Load 4 consecutive points (AoS, dense, 16B-aligned when i0%4==0). Same fmaf
// d2 expression everywhere -> bitwise-consistent between passes.
// ---------------------------------------------------------------------------
__device__ __forceinline__ void load4(const float* __restrict__ sxyz, int i0,
                                      int N, float px[4], float py[4],
                                      float pz[4]) {
  if (i0 + 4 <= N) {
    float4 v0 = *(const float4*)&sxyz[3 * i0];
    float4 v1 = *(const float4*)&sxyz[3 * i0 + 4];
    float4 v2 = *(const float4*)&sxyz[3 * i0 + 8];
    px[0] = v0.x; py[0] = v0.y; pz[0] = v0.z;
    px[1] = v0.w; py[1] = v1.x; pz[1] = v1.y;
    px[2] = v1.z; py[2] = v1.w; pz[2] = v2.x;
    px[3] = v2.y; py[3] = v2.z; pz[3] = v2.w;
  } else {
#pragma unroll
    for (int e = 0; e < 4; ++e) {
      int i = i0 + e; bool ok = i < N;
      px[e] = ok ? sxyz[3 * i] : 0.f;
      py[e] = ok ? sxyz[3 * i + 1] : 0.f;
      pz[e] = ok ? sxyz[3 * i + 2] : 0.f;
    }
  }
}

// ---------------------------------------------------------------------------
// KNN: point-parallel, query-broadcast. 256 threads, 8 queries per block.
// Threshold per query = 16th smallest of the 256 per-thread minima (provable
// upper bound on the true 16th-NN d2). Pass 2 collects survivors (~17);
// exact top-16 by packed (d2,idx) key == lax.top_k tie semantics.
// FAST: batch bounds from prep table (3 dependent loads vs 30).
// ---------------------------------------------------------------------------
template <bool FAST>
__global__ __launch_bounds__(256) void knn_kernel(
    const float* __restrict__ sxyz, const int* __restrict__ bidx,
    const int* __restrict__ fidx, const int* __restrict__ starts,
    const int* __restrict__ ends, int* __restrict__ col, int N, int Q) {
  const int t = threadIdx.x;
  const int qbase = blockIdx.x * KBQ;

  __shared__ float s_min[KBQ][256];
  __shared__ unsigned long long s_cand[KBQ][KCAP];
  __shared__ int s_cnt[KBQ];
  __shared__ float s_thr[KBQ];
  __shared__ float s_qx[KBQ], s_qy[KBQ], s_qz[KBQ];
  __shared__ int s_lo[KBQ], s_hi[KBQ];

  if (t < 2 * KBQ) {
    int qi = qbase + (t & (KBQ - 1));
    if (qi < Q) {
      int fi = fidx[qi];
      int qb = bidx[fi];
      if (FAST) {
        if (t < KBQ) {
          s_qx[t] = sxyz[3 * fi]; s_qy[t] = sxyz[3 * fi + 1]; s_qz[t] = sxyz[3 * fi + 2];
          s_lo[t] = starts[qb];
        } else {
          s_hi[t - KBQ] = ends[qb];
        }
      } else {
        if (t < KBQ) {
          s_qx[t] = sxyz[3 * fi]; s_qy[t] = sxyz[3 * fi + 1]; s_qz[t] = sxyz[3 * fi + 2];
          int a = 0, b = N;
          while (a < b) { int m = (a + b) >> 1; if (bidx[m] < qb) a = m + 1; else b = m; }
          s_lo[t] = a;
        } else {
          int a = 0, b = N;
          while (a < b) { int m = (a + b) >> 1; if (bidx[m] <= qb) a = m + 1; else b = m; }
          s_hi[t - KBQ] = a;
        }
      }
    } else {
      if (t < KBQ) { s_lo[t] = 0; s_qx[t] = s_qy[t] = s_qz[t] = 0.f; }
      else s_hi[t - KBQ] = 0;
    }
  }
  if (t < KBQ) s_cnt[t] = 0;
  __syncthreads();

  float qx[KBQ], qy[KBQ], qz[KBQ], qmin[KBQ];
  int qlo[KBQ], qhi[KBQ];
#pragma unroll
  for (int qi = 0; qi < KBQ; ++qi) {
    qx[qi] = s_qx[qi]; qy[qi] = s_qy[qi]; qz[qi] = s_qz[qi];
    qlo[qi] = s_lo[qi]; qhi[qi] = s_hi[qi];
    qmin[qi] = 3e38f;
  }
  int blo = qlo[0], bhi = qhi[0];
#pragma unroll
  for (int qi = 1; qi < KBQ; ++qi) { blo = min(blo, qlo[qi]); bhi = max(bhi, qhi[qi]); }
  const int base = blo & ~3;

  // --- pass 1: per-thread minima per query ---
  for (int i0 = base + 4 * t; i0 < bhi; i0 += 1024) {
    float px[4], py[4], pz[4];
    load4(sxyz, i0, N, px, py, pz);
#pragma unroll
    for (int e = 0; e < 4; ++e) {
      int i = i0 + e;
#pragma unroll
      for (int qi = 0; qi < KBQ; ++qi) {
        float dx = qx[qi] - px[e], dy = qy[qi] - py[e], dz = qz[qi] - pz[e];
        float d2 = fmaf(dx, dx, fmaf(dy, dy, dz * dz));
        bool v = (i >= qlo[qi]) && (i < qhi[qi]);
        qmin[qi] = fminf(qmin[qi], v ? d2 : 3e38f);
      }
    }
  }
#pragma unroll
  for (int qi = 0; qi < KBQ; ++qi) s_min[qi][t] = qmin[qi];
  __syncthreads();

  // --- threshold: 16th smallest of 256 minima; 32-thread group per query ---
  {
    int qi = t >> 5, u = t & 31;
    float v[8];
#pragma unroll
    for (int s = 0; s < 8; ++s) v[s] = s_min[qi][u + 32 * s];
    float thr = 3e38f;
    for (int r = 0; r < KNN; ++r) {
      float lm = fminf(fminf(fminf(v[0], v[1]), fminf(v[2], v[3])),
                       fminf(fminf(v[4], v[5]), fminf(v[6], v[7])));
      float gm = lm;
      gm = fminf(gm, __shfl_xor(gm, 1, 64));
      gm = fminf(gm, __shfl_xor(gm, 2, 64));
      gm = fminf(gm, __shfl_xor(gm, 4, 64));
      gm = fminf(gm, __shfl_xor(gm, 8, 64));
      gm = fminf(gm, __shfl_xor(gm, 16, 64));
      unsigned long long b = __ballot(lm == gm);
      unsigned mask = (unsigned)((b >> (t & 32)) & 0xffffffffull);
      int win = __ffs(mask) - 1;
      if (u == win) {  // knock exactly one instance
        if (v[0] == gm) v[0] = 3e38f; else if (v[1] == gm) v[1] = 3e38f;
        else if (v[2] == gm) v[2] = 3e38f; else if (v[3] == gm) v[3] = 3e38f;
        else if (v[4] == gm) v[4] = 3e38f; else if (v[5] == gm) v[5] = 3e38f;
        else if (v[6] == gm) v[6] = 3e38f; else v[7] = 3e38f;
      }
      thr = gm;
    }
    if (u == 0)
      s_thr[qi] = (s_hi[qi] - s_lo[qi] <= KCAP) ? 3e38f : thr;  // tiny-segment exact
  }
  __syncthreads();

  float qthr[KBQ];
#pragma unroll
  for (int qi = 0; qi < KBQ; ++qi) qthr[qi] = s_thr[qi];

  // --- pass 2: collect survivors ---
  for (int i0 = base + 4 * t; i0 < bhi; i0 += 1024) {
    float px[4], py[4], pz[4];
    load4(sxyz, i0, N, px, py, pz);
#pragma unroll
    for (int e = 0; e < 4; ++e) {
      int i = i0 + e;
#pragma unroll
      for (int qi = 0; qi < KBQ; ++qi) {
        float dx = qx[qi] - px[e], dy = qy[qi] - py[e], dz = qz[qi] - pz[e];
        float d2 = fmaf(dx, dx, fmaf(dy, dy, dz * dz));
        if (i >= qlo[qi] && i < qhi[qi] && d2 <= qthr[qi]) {
          int pos = atomicAdd(&s_cnt[qi], 1);
          if (pos < KCAP)
            s_cand[qi][pos] =
                (((unsigned long long)__float_as_uint(d2)) << 32) | (unsigned)i;
        }
      }
    }
  }
  __syncthreads();

  // --- extraction: 32-thread group per query, 16 exact min rounds ---
  {
    int qi = t >> 5, u = t & 31;
    int M = min(s_cnt[qi], KCAP);
    for (int r = 0; r < KNN; ++r) {
      unsigned long long lm = ~0ull; int ls = -1;
      for (int s = u; s < M; s += 32) {
        unsigned long long vv = s_cand[qi][s];
        if (vv < lm) { lm = vv; ls = s; }
      }
      unsigned long long gm = lm, o;
      o = __shfl_xor(gm, 1, 64); if (o < gm) gm = o;
      o = __shfl_xor(gm, 2, 64); if (o < gm) gm = o;
      o = __shfl_xor(gm, 4, 64); if (o < gm) gm = o;
      o = __shfl_xor(gm, 8, 64); if (o < gm) gm = o;
      o = __shfl_xor(gm, 16, 64); if (o < gm) gm = o;
      unsigned long long b = __ballot(lm == gm);
      unsigned mask = (unsigned)((b >> (t & 32)) & 0xffffffffull);
      int win = __ffs(mask) - 1;
      if (u == win && ls >= 0 && gm != ~0ull) {
        s_cand[qi][ls] = ~0ull;  // intra-wave group -> in-order LDS
        col[(size_t)(qbase + qi) * KNN + r] = (int)(unsigned)(gm & 0xffffffffull);
      }
    }
  }
}

// ---------------------------------------------------------------------------
// Fused per-query kernel. LDS 19.0 KB -> 8 blocks/CU (16 waves/CU): leaf read
// from global (16-lane broadcast, R2/R4-verified), hidden|cls aliased,
// fallback mat reuses dead ew/fc region. Math order identical to R5.
// ---------------------------------------------------------------------------
#define OFF_EDGE 0     // 16 x 130
#define OFF_B 2080     // union: hidden 16x68 | cls 16x130
#define OFF_EW 4160    // 16 x 12  (dead after MLP1; fallback mat reuses)
#define OFF_FC 4352    // 16 x 20
#define S_TOTAL 4672

template <bool EXT>
__global__ __launch_bounds__(128) void fused_kernel(
    const float* __restrict__ sxyz,
    const int* __restrict__ fidx,
    const float* __restrict__ gcn,
    const float* __restrict__ leaf,
    const float* __restrict__ W1, const float* __restrict__ b1,
    const float* __restrict__ W2, const float* __restrict__ b2,
    const float* __restrict__ Wl, const float* __restrict__ bl,
    const int* __restrict__ col,
    float* __restrict__ matw, float* __restrict__ out) {
  const int q = blockIdx.x;
  const int t = threadIdx.x;

  __shared__ __align__(16) float S[S_TOTAL];
  __shared__ int s_col[KNN];
  __shared__ float s_rna[24];
  __shared__ float s_rnb[3][KNN];

  if (t < KNN) s_col[t] = col[q * KNN + t];
  __syncthreads();

  for (int v = t; v < KNN * 20; v += 128)
    S[OFF_FC + v] = gcn[(size_t)s_col[v / 20] * 148 + 128 + (v % 20)];
  if (t < KNN) {
    int fi = fidx[q];
    float qx = sxyz[3 * fi], qy = sxyz[3 * fi + 1], qz = sxyz[3 * fi + 2];
    int j = s_col[t];
    float jx = sxyz[3 * j], jy = sxyz[3 * j + 1], jz = sxyz[3 * j + 2];
    float dx = qx - jx, dy = qy - jy, dz = qz - jz;
    float dist = sqrtf(dx * dx + dy * dy + dz * dz);
    float* e = &S[OFF_EW + t * 12];
    e[0] = qx; e[1] = qy; e[2] = qz;
    e[3] = jx; e[4] = jy; e[5] = jz;
    e[6] = dx; e[7] = dy; e[8] = dz; e[9] = dist;
  }
  __syncthreads();

  // MLP layer 1 -> hidden (region B, stride 68)
  for (int r = 0; r < 8; ++r) {
    int o = r * 128 + t;
    int k = o >> 6, jj = o & 63;
    float acc0 = b1[jj];
#pragma unroll
    for (int i = 0; i < 10; ++i)
      acc0 = fmaf(S[OFF_EW + k * 12 + i], W1[i * 64 + jj], acc0);
    S[OFF_B + k * 68 + jj] = fmaxf(acc0, 0.0f);
  }
  __syncthreads();

  // MLP layer 2: W2 in-loop (L1-resident), t = output channel
  float acc[KNN];
#pragma unroll
  for (int k = 0; k < KNN; ++k) acc[k] = b2[t];
#pragma unroll
  for (int j4 = 0; j4 < 16; ++j4) {
    float w0 = W2[(4 * j4 + 0) * 128 + t];
    float w1 = W2[(4 * j4 + 1) * 128 + t];
    float w2 = W2[(4 * j4 + 2) * 128 + t];
    float w3 = W2[(4 * j4 + 3) * 128 + t];
#pragma unroll
    for (int k = 0; k < KNN; ++k) {
      float4 h = *(const float4*)&S[OFF_B + k * 68 + 4 * j4];
      acc[k] = fmaf(h.x, w0, acc[k]);
      acc[k] = fmaf(h.y, w1, acc[k]);
      acc[k] = fmaf(h.z, w2, acc[k]);
      acc[k] = fmaf(h.w, w3, acc[k]);
    }
  }
#pragma unroll
  for (int k = 0; k < KNN; ++k) S[OFF_EDGE + k * 130 + t] = acc[k];
  __syncthreads();  // hidden reads done before cls overwrites region B

  // cls GEMV -> region B (stride 130)
#pragma unroll
  for (int k = 0; k < KNN; ++k) acc[k] = bl[t];
#pragma unroll
  for (int c = 0; c < 20; ++c) {
    float wv = Wl[c * 128 + t];
#pragma unroll
    for (int k = 0; k < KNN; ++k) acc[k] = fmaf(S[OFF_FC + k * 20 + c], wv, acc[k]);
  }
#pragma unroll
  for (int k = 0; k < KNN; ++k) S[OFF_B + k * 130 + t] = acc[k];
  __syncthreads();

  // 72 norm jobs (leaf/featH from global, edge/cls from LDS)
  if (t < 72) {
    float s0 = 0, s1 = 0, s2 = 0, s3 = 0;
    if (t < 24 || t >= 56) {
      const float4* p = (t < 24)
          ? (const float4*)(leaf + (size_t)q * 3072 + (t / 3) * 384 + (t % 3) * 128)
          : (const float4*)(gcn + (size_t)s_col[t - 56] * 148);
#pragma unroll 4
      for (int h = 0; h < 32; ++h) {
        float4 v = p[h];
        s0 = fmaf(v.x, v.x, s0); s1 = fmaf(v.y, v.y, s1);
        s2 = fmaf(v.z, v.z, s2); s3 = fmaf(v.w, v.w, s3);
      }
    } else {
      const float* p = (t < 40) ? &S[OFF_EDGE + (t - 24) * 130] : &S[OFF_B + (t - 40) * 130];
#pragma unroll 4
      for (int h = 0; h < 128; h += 4) {
        float2 v0 = *(const float2*)&p[h];
        float2 v1 = *(const float2*)&p[h + 2];
        s0 = fmaf(v0.x, v0.x, s0); s1 = fmaf(v0.y, v0.y, s1);
        s2 = fmaf(v1.x, v1.x, s2); s3 = fmaf(v1.y, v1.y, s3);
      }
    }
    float rn = 1.0f / fmaxf(sqrtf((s0 + s1) + (s2 + s3)), 1e-8f);
    if (t < 24) s_rna[t] = rn;
    else if (t < 40) s_rnb[0][t - 24] = rn;
    else if (t < 56) s_rnb[1][t - 40] = rn;
    else s_rnb[2][t - 56] = rn;
  }
  __syncthreads();

  // 128 cosine dots -> mat (leaf via global broadcast reads)
  {
    int l = t >> 4, k = t & 15;
    const float* a0 = leaf + (size_t)q * 3072 + l * 384;
    const float* be = &S[OFF_EDGE + k * 130];
    const float* bc = &S[OFF_B + k * 130];
    const float* bf = gcn + (size_t)s_col[k] * 148;
    float d0 = 0, d1 = 0, d2 = 0;
    for (int h = 0; h < 128; h += 4) {
      float4 va0 = *(const float4*)&a0[h];
      float4 va1 = *(const float4*)&a0[128 + h];
      float4 va2 = *(const float4*)&a0[256 + h];
      float4 vbf = *(const float4*)&bf[h];
      float2 ve0 = *(const float2*)&be[h];
      float2 ve1 = *(const float2*)&be[h + 2];
      float2 vc0 = *(const float2*)&bc[h];
      float2 vc1 = *(const float2*)&bc[h + 2];
      d0 = fmaf(va0.x, ve0.x, d0); d0 = fmaf(va0.y, ve0.y, d0);
      d0 = fmaf(va0.z, ve1.x, d0); d0 = fmaf(va0.w, ve1.y, d0);
      d1 = fmaf(va1.x, vc0.x, d1); d1 = fmaf(va1.y, vc0.y, d1);
      d1 = fmaf(va1.z, vc1.x, d1); d1 = fmaf(va1.w, vc1.y, d1);
      d2 = fmaf(va2.x, vbf.x, d2); d2 = fmaf(va2.y, vbf.y, d2);
      d2 = fmaf(va2.z, vbf.z, d2); d2 = fmaf(va2.w, vbf.w, d2);
    }
    float m = (d0 * s_rna[l * 3 + 0] * s_rnb[0][k] +
               d1 * s_rna[l * 3 + 1] * s_rnb[1][k]) * 0.25f +
              d2 * s_rna[l * 3 + 2] * s_rnb[2][k] * 0.5f;
    if (EXT) {
      matw[(size_t)q * 128 + t] = m;
      return;
    }
    S[OFF_EW + l * 17 + k] = m;  // ew/fc dead; reuse as mat
  }
  __syncthreads();
  if (t >= 64) return;

  // fallback inline auction
  float* s_mat = &S[OFF_EW];
  float mrow[KNN];
#pragma unroll
  for (int c = 0; c < KNN; ++c) mrow[c] = s_mat[(t & 7) * 17 + c];
  int ass = -1;
  float cost = 0.f;
  for (int it = 0; it < 1024; ++it) {
    float v1 = -3e38f, v2 = -3e38f; int c1 = 0;
#pragma unroll
    for (int c = 0; c < KNN; ++c) {
      float costc = __shfl(cost, c, 64);
      float v = mrow[c] - costc;
      if (v > v1) { v2 = v1; v1 = v; c1 = c; }
      else if (v > v2) v2 = v;
    }
    int bidc = (t < 8 && ass < 0) ? c1 : -1;
    float bidv = v1 - v2 + 0.125f;
    float high = -3e38f; int hb = -1;
#pragma unroll
    for (int r = 0; r < 8; ++r) {
      int bc = __shfl(bidc, r, 64);
      float bv = __shfl(bidv, r, 64);
      if (bc == t && bv > high) { high = bv; hb = r; }
    }
    if (t < 16 && hb >= 0) cost += high;
    int hb_c = __shfl(hb, bidc < 0 ? 0 : bidc, 64);
    int hb_a = __shfl(hb, ass < 0 ? 0 : ass, 64);
    if (t < 8) {
      if (ass >= 0 && hb_a >= 0) ass = -1;
      if (bidc >= 0 && hb_c == t) ass = bidc;
    }
    if (__ballot((t < 8) ? (ass >= 0) : 1) == ~0ull) break;
  }
  float s = 0.f;
#pragma unroll
  for (int r = 0; r < 8; ++r) {
    int a = __shfl(ass, r, 64);
    if (t == 0) s += s_mat[r * 17 + a];
  }
  if (t == 0) out[q] = s * 0.125f;
}

// ---------------------------------------------------------------------------
// Auction kernel: 16 lanes/query, reg+shfl synchronous Jacobi, exact
// reference tie-breaks (strict > scans: lowest col / lowest row).
// ---------------------------------------------------------------------------
__global__ __launch_bounds__(256) void auction_kernel(
    const float* __restrict__ matw, float* __restrict__ out, int Q) {
  const int t = threadIdx.x;
  const int lane = t & 63;
  const int gj = lane & 15;
  const int gb = lane & ~15;
  const int q = blockIdx.x * 16 + (t >> 6) * 4 + (lane >> 4);
  const bool valid = q < Q;

  float mrow[KNN];
  if (valid && gj < 8) {
    const float4* mp = (const float4*)(matw + (size_t)q * 128 + gj * 16);
    float4 a = mp[0], b = mp[1], c = mp[2], d = mp[3];
    mrow[0] = a.x; mrow[1] = a.y; mrow[2] = a.z; mrow[3] = a.w;
    mrow[4] = b.x; mrow[5] = b.y; mrow[6] = b.z; mrow[7] = b.w;
    mrow[8] = c.x; mrow[9] = c.y; mrow[10] = c.z; mrow[11] = c.w;
    mrow[12] = d.x; mrow[13] = d.y; mrow[14] = d.z; mrow[15] = d.w;
  } else {
#pragma unroll
    for (int c = 0; c < KNN; ++c) mrow[c] = 0.f;
  }
  int ass = (valid && gj < 8) ? -1 : 0;
  float cost = 0.f;

  for (int it = 0; it < 512; ++it) {
    float v1 = -3e38f, v2 = -3e38f; int c1 = 0;
#pragma unroll
    for (int c = 0; c < KNN; ++c) {
      float costc = __shfl(cost, gb + c, 64);
      float v = mrow[c] - costc;
      if (v > v1) { v2 = v1; v1 = v; c1 = c; }
      else if (v > v2) v2 = v;
    }
    int bidc = (valid && gj < 8 && ass < 0) ? c1 : -1;
    float bidv = v1 - v2 + 0.125f;  // eps = 1/L

    float high = -3e38f; int hb = -1;
#pragma unroll
    for (int r = 0; r < 8; ++r) {
      int bc = __shfl(bidc, gb + r, 64);
      float bv = __shfl(bidv, gb + r, 64);
      if (bc == gj && bv > high) { high = bv; hb = r; }
    }
    if (hb >= 0) cost += high;

    int hb_c = __shfl(hb, gb + (bidc < 0 ? 0 : bidc), 64);
    int hb_a = __shfl(hb, gb + (ass < 0 ? 0 : ass), 64);
    if (valid && gj < 8) {
      if (ass >= 0 && hb_a >= 0) ass = -1;
      if (bidc >= 0 && hb_c == gj) ass = bidc;
    }
    if (__ballot(ass >= 0) == ~0ull) break;
  }

  float val = 0.f;
  if (valid && gj < 8) {
#pragma unroll
    for (int c = 0; c < KNN; ++c) val = (ass == c) ? mrow[c] : val;
  }
  val += __shfl_xor(val, 1, 64);
  val += __shfl_xor(val, 2, 64);
  val += __shfl_xor(val, 4, 64);
  if (valid && gj == 0) out[q] = val * 0.125f;
}

// ---------------------------------------------------------------------------
extern "C" void kernel_launch(void* const* d_in, const int* in_sizes, int n_in,
                              void* d_out, int out_size, void* d_ws, size_t ws_size,
                              hipStream_t stream) {
  const float* sxyz = (const float*)d_in[0];
  const int* bidx = (const int*)d_in[1];
  const int* fidx = (const int*)d_in[2];
  const float* gcn = (const float*)d_in[3];
  const float* leaf = (const float*)d_in[4];
  const float* W1 = (const float*)d_in[5];
  const float* b1 = (const float*)d_in[6];
  const float* W2 = (const float*)d_in[7];
  const float* b2 = (const float*)d_in[8];
  const float* Wl = (const float*)d_in[9];
  const float* bl = (const float*)d_in[10];
  float* out = (float*)d_out;

  const int N = in_sizes[0] / 3;
  const int Q = in_sizes[2];

  char* ws = (char*)d_ws;
  int* col = (int*)ws;                                    // Q*16 ints
  int* starts = (int*)(ws + (size_t)Q * KNN * 4);         // 4096 ints
  int* ends = starts + 4096;
  float* matw = (float*)(ws + (size_t)Q * KNN * 4 + 32768);
  const size_t need_bounds = (size_t)Q * KNN * 4 + 32768;
  const size_t need_full = need_bounds + (size_t)Q * 128 * 4;

  if (ws_size >= need_bounds) {
    prep_bounds<<<(N + 255) / 256, 256, 0, stream>>>(bidx, N, starts, ends);
    knn_kernel<true><<<(Q + KBQ - 1) / KBQ, 256, 0, stream>>>(
        sxyz, bidx, fidx, starts, ends, col, N, Q);
  } else {
    knn_kernel<false><<<(Q + KBQ - 1) / KBQ, 256, 0, stream>>>(
        sxyz, bidx, fidx, nullptr, nullptr, col, N, Q);
  }
  if (ws_size >= need_full) {
    fused_kernel<true><<<Q, 128, 0, stream>>>(sxyz, fidx, gcn, leaf, W1, b1, W2,
                                              b2, Wl, bl, col, matw, out);
    auction_kernel<<<(Q + 15) / 16, 256, 0, stream>>>(matw, out, Q);
  } else {
    fused_kernel<false><<<Q, 128, 0, stream>>>(sxyz, fidx, gcn, leaf, W1, b1, W2,
                                               b2, Wl, bl, col, nullptr, out);
  }
}